// Round 8
// baseline (218.579 us; speedup 1.0000x reference)
//
#include <hip/hip_runtime.h>

typedef _Float16 f16;
typedef _Float16 f16x8 __attribute__((ext_vector_type(8)));
typedef float f32x4 __attribute__((ext_vector_type(4)));
typedef float fl4 __attribute__((ext_vector_type(4)));

#define NEG_INF_F (-1e10f)

// ---------------- prep: all 5 weight transposes + class_labels pad/convert ----------
// idx < 1048576: mw1t/vw1t 512x1024 (k-fast writes); < 1835008: mw2t/vw2t/aw1t 512x512;
// else: cl_h (1152,1024) zero-padded from CL (1152,1000)
__global__ __launch_bounds__(256) void prep(const float* __restrict__ mw1,
                                            const float* __restrict__ vw1,
                                            const float* __restrict__ mw2,
                                            const float* __restrict__ vw2,
                                            const float* __restrict__ aw1,
                                            const float* __restrict__ cl,
                                            f16* __restrict__ mw1t, f16* __restrict__ vw1t,
                                            f16* __restrict__ mw2t, f16* __restrict__ vw2t,
                                            f16* __restrict__ aw1t, f16* __restrict__ cl_h) {
    int i = blockIdx.x * 256 + threadIdx.x;
    if (i < 1048576) {
        int seg = i >> 19;
        int j = i & 524287;
        int k = j & 1023, n = j >> 10;
        if (seg == 0) mw1t[n * 1024 + k] = (f16)mw1[k * 512 + n];
        else          vw1t[n * 1024 + k] = (k < 1000) ? (f16)vw1[k * 512 + n] : (f16)0.f;
    } else if (i < 1835008) {
        int j = i - 1048576;
        int seg = j >> 18;
        int r = j & 262143;
        int k = r & 511, n = r >> 9;
        const float* src = (seg == 0) ? mw2 : (seg == 1) ? vw2 : aw1;
        f16* dst = (seg == 0) ? mw2t : (seg == 1) ? vw2t : aw1t;
        dst[n * 512 + k] = (f16)src[k * 512 + n];
    } else {
        int j = i - 1835008;
        int r = j >> 10, k = j & 1023;
        cl_h[j] = (k < 1000) ? (f16)cl[r * 1000 + k] : (f16)0.f;
    }
}

__device__ __forceinline__ f16x8 cvt8(const float* p) {
    fl4 x = *(const fl4*)p;
    fl4 y = *(const fl4*)(p + 4);
    f16x8 r;
    #pragma unroll
    for (int e = 0; e < 4; e++) { r[e] = (f16)x[e]; r[4 + e] = (f16)y[e]; }
    return r;
}

// ---------------- stage 1: men1 = relu(ME@mw1t + mb1)  [A=f32, rows 2048, bx<32]
//                            vis1 = relu(cl_h@vw1t + vb1) [A=f16, rows 1152, bx>=32]
__global__ __launch_bounds__(256) void gemm_s1(const float* __restrict__ Af,
                                               const f16* __restrict__ Ah,
                                               const f16* __restrict__ Wm, const f16* __restrict__ Wv,
                                               const float* __restrict__ bm, const float* __restrict__ bv,
                                               f16* __restrict__ om, f16* __restrict__ ov) {
    int lane = threadIdx.x & 63, w = threadIdx.x >> 6;
    int wr = w >> 1, wc = w & 1;
    int rl = lane & 15, kg = lane >> 4;
    bool isv = blockIdx.x >= 32;
    int mb = isv ? blockIdx.x - 32 : blockIdx.x;
    const f16* Wt = isv ? Wv : Wm;
    const float* bias = isv ? bv : bm;
    f16* out = isv ? ov : om;
    int m0 = mb * 64 + wr * 32, n0 = blockIdx.y * 64 + wc * 32;

    f32x4 acc[2][2] = {};
    const f16* b0p = Wt + (n0 + rl) * 1024 + kg * 8;
    const f16* b1p = b0p + 16 * 1024;
    const float* af0 = Af + (m0 + rl) * 1024 + kg * 8;
    const float* af1 = af0 + 16 * 1024;
    const f16* ah0 = Ah + (m0 + rl) * 1024 + kg * 8;
    const f16* ah1 = ah0 + 16 * 1024;

    for (int k0 = 0; k0 < 1024; k0 += 32) {
        f16x8 a0, a1;
        if (!isv) { a0 = cvt8(af0 + k0); a1 = cvt8(af1 + k0); }
        else      { a0 = *(const f16x8*)(ah0 + k0); a1 = *(const f16x8*)(ah1 + k0); }
        f16x8 b0 = *(const f16x8*)(b0p + k0);
        f16x8 b1 = *(const f16x8*)(b1p + k0);
        acc[0][0] = __builtin_amdgcn_mfma_f32_16x16x32_f16(a0, b0, acc[0][0], 0, 0, 0);
        acc[0][1] = __builtin_amdgcn_mfma_f32_16x16x32_f16(a0, b1, acc[0][1], 0, 0, 0);
        acc[1][0] = __builtin_amdgcn_mfma_f32_16x16x32_f16(a1, b0, acc[1][0], 0, 0, 0);
        acc[1][1] = __builtin_amdgcn_mfma_f32_16x16x32_f16(a1, b1, acc[1][1], 0, 0, 0);
    }
    #pragma unroll
    for (int fi = 0; fi < 2; fi++)
        #pragma unroll
        for (int fj = 0; fj < 2; fj++) {
            int col = n0 + fj * 16 + rl;
            float bv2 = bias[col];
            #pragma unroll
            for (int r = 0; r < 4; r++) {
                int row = m0 + fi * 16 + kg * 4 + r;
                out[row * 512 + col] = (f16)fmaxf(acc[fi][fj][r] + bv2, 0.f);
            }
        }
}

// ---------------- stage 2: menh = men1@mw2t + mb2; vish = vis1@vw2t + vb2 (K=512)
__global__ __launch_bounds__(256) void gemm_s2(const f16* __restrict__ Am,
                                               const f16* __restrict__ Av,
                                               const f16* __restrict__ Wm, const f16* __restrict__ Wv,
                                               const float* __restrict__ bm, const float* __restrict__ bv,
                                               f16* __restrict__ om, f16* __restrict__ ov) {
    int lane = threadIdx.x & 63, w = threadIdx.x >> 6;
    int wr = w >> 1, wc = w & 1;
    int rl = lane & 15, kg = lane >> 4;
    bool isv = blockIdx.x >= 32;
    int mb = isv ? blockIdx.x - 32 : blockIdx.x;
    const f16* A = isv ? Av : Am;
    const f16* Wt = isv ? Wv : Wm;
    const float* bias = isv ? bv : bm;
    f16* out = isv ? ov : om;
    int m0 = mb * 64 + wr * 32, n0 = blockIdx.y * 64 + wc * 32;

    f32x4 acc[2][2] = {};
    const f16* a0p = A + (m0 + rl) * 512 + kg * 8;
    const f16* a1p = a0p + 16 * 512;
    const f16* b0p = Wt + (n0 + rl) * 512 + kg * 8;
    const f16* b1p = b0p + 16 * 512;

    for (int k0 = 0; k0 < 512; k0 += 32) {
        f16x8 a0 = *(const f16x8*)(a0p + k0);
        f16x8 a1 = *(const f16x8*)(a1p + k0);
        f16x8 b0 = *(const f16x8*)(b0p + k0);
        f16x8 b1 = *(const f16x8*)(b1p + k0);
        acc[0][0] = __builtin_amdgcn_mfma_f32_16x16x32_f16(a0, b0, acc[0][0], 0, 0, 0);
        acc[0][1] = __builtin_amdgcn_mfma_f32_16x16x32_f16(a0, b1, acc[0][1], 0, 0, 0);
        acc[1][0] = __builtin_amdgcn_mfma_f32_16x16x32_f16(a1, b0, acc[1][0], 0, 0, 0);
        acc[1][1] = __builtin_amdgcn_mfma_f32_16x16x32_f16(a1, b1, acc[1][1], 0, 0, 0);
    }
    #pragma unroll
    for (int fi = 0; fi < 2; fi++)
        #pragma unroll
        for (int fj = 0; fj < 2; fj++) {
            int col = n0 + fj * 16 + rl;
            float bv2 = bias[col];
            #pragma unroll
            for (int r = 0; r < 4; r++) {
                int row = m0 + fi * 16 + kg * 4 + r;
                out[row * 512 + col] = (f16)(acc[fi][fj][r] + bv2);
            }
        }
}

// ---------------- fused attention, occupancy-optimized ----------------
// grid (18 cp, 32 b), 256 thr (4 waves), launch_bounds(256,3) -> 12 waves/CU,
// all 576 blocks resident in ONE round (576 < 3*256). No LDS staging (aw1t is
// L2-resident; R2 showed staging neutral). Wave w: mh=w&1 (32 m-rows), jq=w>>1;
// 4 j-passes, psum accumulated in registers; 2-slot LDS reduce; direct masked store.
__global__ __launch_bounds__(256, 3) void attn_f2(const f16* __restrict__ men,
                                                  const f16* __restrict__ vis,
                                                  const f16* __restrict__ aw1t,
                                                  const float* __restrict__ ab1,
                                                  const float* __restrict__ aw2,
                                                  const float* __restrict__ ab2,
                                                  const float* __restrict__ maskm,
                                                  const float* __restrict__ maskc,
                                                  float* __restrict__ out) {
    __shared__ float red[2][2][64];  // [jq][c][m]

    int t = threadIdx.x, lane = t & 63, w = t >> 6;
    int mh = w & 1, jq = w >> 1;
    int cp = blockIdx.x, b = blockIdx.y, c0 = cp * 2;
    int rl = lane & 15, kg = lane >> 4;

    const f16* menb = men + (b * 64 + mh * 32 + rl) * 512 + kg * 8;
    const f16* visb = vis + (b * 36 + c0) * 512 + kg * 8;

    float psum0[2][4] = {}, psum1[2][4] = {};

    for (int p = 0; p < 4; p++) {
        int j0 = p * 128 + jq * 64;
        const f16* awb = aw1t + (j0 + rl) * 512 + kg * 8;

        f32x4 acc0[2][4] = {}, acc1[2][4] = {};
        for (int k0 = 0; k0 < 512; k0 += 32) {
            f16x8 vv0 = *(const f16x8*)(visb + k0);
            f16x8 vv1 = *(const f16x8*)(visb + 512 + k0);
            f16x8 mm[2], bf[4];
            #pragma unroll
            for (int fi = 0; fi < 2; fi++)
                mm[fi] = *(const f16x8*)(menb + fi * 16 * 512 + k0);
            #pragma unroll
            for (int fj = 0; fj < 4; fj++)
                bf[fj] = *(const f16x8*)(awb + fj * 16 * 512 + k0);

            #pragma unroll
            for (int fi = 0; fi < 2; fi++) {
                f16x8 a0 = mm[fi] * vv0;
                #pragma unroll
                for (int fj = 0; fj < 4; fj++)
                    acc0[fi][fj] = __builtin_amdgcn_mfma_f32_16x16x32_f16(a0, bf[fj], acc0[fi][fj], 0, 0, 0);
            }
            #pragma unroll
            for (int fi = 0; fi < 2; fi++) {
                f16x8 a1 = mm[fi] * vv1;
                #pragma unroll
                for (int fj = 0; fj < 4; fj++)
                    acc1[fi][fj] = __builtin_amdgcn_mfma_f32_16x16x32_f16(a1, bf[fj], acc1[fi][fj], 0, 0, 0);
            }
        }

        // fp32 epilogue for this j-pass
        float ab1v[4], aw2v[4];
        #pragma unroll
        for (int fj = 0; fj < 4; fj++) {
            int j = j0 + fj * 16 + rl;
            ab1v[fj] = ab1[j];
            aw2v[fj] = aw2[j];
        }
        float part0[2][4], part1[2][4];
        #pragma unroll
        for (int fi = 0; fi < 2; fi++)
            #pragma unroll
            for (int r = 0; r < 4; r++) {
                float s0 = 0.f, s1 = 0.f;
                #pragma unroll
                for (int fj = 0; fj < 4; fj++) {
                    s0 += fmaxf(acc0[fi][fj][r] + ab1v[fj], 0.f) * aw2v[fj];
                    s1 += fmaxf(acc1[fi][fj][r] + ab1v[fj], 0.f) * aw2v[fj];
                }
                part0[fi][r] = s0;
                part1[fi][r] = s1;
            }
        #pragma unroll
        for (int mask = 1; mask < 16; mask <<= 1)
            #pragma unroll
            for (int fi = 0; fi < 2; fi++)
                #pragma unroll
                for (int r = 0; r < 4; r++) {
                    part0[fi][r] += __shfl_xor(part0[fi][r], mask);
                    part1[fi][r] += __shfl_xor(part1[fi][r], mask);
                }
        #pragma unroll
        for (int fi = 0; fi < 2; fi++)
            #pragma unroll
            for (int r = 0; r < 4; r++) {
                psum0[fi][r] += part0[fi][r];
                psum1[fi][r] += part1[fi][r];
            }
    }

    // static select (rule #20): lane rl<8 owns (fi=rl>>2, r=rl&3)
    float myv0 = 0.f, myv1 = 0.f;
    #pragma unroll
    for (int fi = 0; fi < 2; fi++)
        #pragma unroll
        for (int r = 0; r < 4; r++) {
            bool sel = (rl == fi * 4 + r);
            myv0 = sel ? psum0[fi][r] : myv0;
            myv1 = sel ? psum1[fi][r] : myv1;
        }
    if (rl < 8) {
        int m = mh * 32 + (rl >> 2) * 16 + kg * 4 + (rl & 3);
        red[jq][0][m] = myv0;
        red[jq][1][m] = myv1;
    }
    __syncthreads();

    if (t < 128) {
        int ci = t >> 6, m = t & 63;
        float s = red[0][ci][m] + red[1][ci][m];
        int c = c0 + ci;
        float v = (s + ab2[0]) * maskm[b * 64 + m] * maskc[b * 36 + c];
        out[(b * 64 + m) * 36 + c] = (v != 0.f) ? v : NEG_INF_F;
    }
}

extern "C" void kernel_launch(void* const* d_in, const int* in_sizes, int n_in,
                              void* d_out, int out_size, void* d_ws, size_t ws_size,
                              hipStream_t stream) {
    const float* ME  = (const float*)d_in[0];   // (32,64,1024)
    const float* CL  = (const float*)d_in[1];   // (32,36,1000)
    const float* MM  = (const float*)d_in[2];   // (32,64)
    const float* CM  = (const float*)d_in[3];   // (32,36)
    const float* VW1 = (const float*)d_in[4];   // (1000,512)
    const float* VB1 = (const float*)d_in[5];
    const float* VW2 = (const float*)d_in[6];   // (512,512)
    const float* VB2 = (const float*)d_in[7];
    const float* MW1 = (const float*)d_in[8];   // (1024,512)
    const float* MB1 = (const float*)d_in[9];
    const float* MW2 = (const float*)d_in[10];  // (512,512)
    const float* MB2 = (const float*)d_in[11];
    const float* AW1 = (const float*)d_in[12];  // (512,512)
    const float* AB1 = (const float*)d_in[13];
    const float* AW2 = (const float*)d_in[14];  // (512,1)
    const float* AB2 = (const float*)d_in[15];  // (1,)
    float* out = (float*)d_out;

    char* ws = (char*)d_ws;
    f16* cl_h  = (f16*)ws; ws += (size_t)1152 * 1024 * 2;
    f16* mw1t  = (f16*)ws; ws += (size_t)512 * 1024 * 2;
    f16* vw1t  = (f16*)ws; ws += (size_t)512 * 1024 * 2;
    f16* mw2t  = (f16*)ws; ws += (size_t)512 * 512 * 2;
    f16* vw2t  = (f16*)ws; ws += (size_t)512 * 512 * 2;
    f16* aw1t  = (f16*)ws; ws += (size_t)512 * 512 * 2;
    f16* men1  = (f16*)ws; ws += (size_t)2048 * 512 * 2;
    f16* menh  = (f16*)ws; ws += (size_t)2048 * 512 * 2;
    f16* vis1  = (f16*)ws; ws += (size_t)1152 * 512 * 2;
    f16* vish  = (f16*)ws; ws += (size_t)1152 * 512 * 2;

    prep<<<11776, 256, 0, stream>>>(MW1, VW1, MW2, VW2, AW1, CL,
                                    mw1t, vw1t, mw2t, vw2t, aw1t, cl_h);
    gemm_s1<<<dim3(50, 8), 256, 0, stream>>>(ME, cl_h, mw1t, vw1t, MB1, VB1, men1, vis1);
    gemm_s2<<<dim3(50, 8), 256, 0, stream>>>(men1, vis1, mw2t, vw2t, MB2, VB2, menh, vish);
    attn_f2<<<dim3(18, 32), 256, 0, stream>>>(menh, vish, aw1t, AB1, AW2, AB2, MM, CM, out);
}

// Round 9
// 217.379 us; speedup vs baseline: 1.0055x; 1.0055x over previous
//
#include <hip/hip_runtime.h>

typedef _Float16 f16;
typedef _Float16 f16x8 __attribute__((ext_vector_type(8)));
typedef float f32x4 __attribute__((ext_vector_type(4)));
typedef float fl4 __attribute__((ext_vector_type(4)));

#define NEG_INF_F (-1e10f)

// ---------------- prep: all 5 weight transposes + class_labels pad/convert ----------
__global__ __launch_bounds__(256) void prep(const float* __restrict__ mw1,
                                            const float* __restrict__ vw1,
                                            const float* __restrict__ mw2,
                                            const float* __restrict__ vw2,
                                            const float* __restrict__ aw1,
                                            const float* __restrict__ cl,
                                            f16* __restrict__ mw1t, f16* __restrict__ vw1t,
                                            f16* __restrict__ mw2t, f16* __restrict__ vw2t,
                                            f16* __restrict__ aw1t, f16* __restrict__ cl_h) {
    int i = blockIdx.x * 256 + threadIdx.x;
    if (i < 1048576) {
        int seg = i >> 19;
        int j = i & 524287;
        int k = j & 1023, n = j >> 10;
        if (seg == 0) mw1t[n * 1024 + k] = (f16)mw1[k * 512 + n];
        else          vw1t[n * 1024 + k] = (k < 1000) ? (f16)vw1[k * 512 + n] : (f16)0.f;
    } else if (i < 1835008) {
        int j = i - 1048576;
        int seg = j >> 18;
        int r = j & 262143;
        int k = r & 511, n = r >> 9;
        const float* src = (seg == 0) ? mw2 : (seg == 1) ? vw2 : aw1;
        f16* dst = (seg == 0) ? mw2t : (seg == 1) ? vw2t : aw1t;
        dst[n * 512 + k] = (f16)src[k * 512 + n];
    } else {
        int j = i - 1835008;
        int r = j >> 10, k = j & 1023;
        cl_h[j] = (k < 1000) ? (f16)cl[r * 1000 + k] : (f16)0.f;
    }
}

__device__ __forceinline__ f16x8 cvt8(const float* p) {
    fl4 x = *(const fl4*)p;
    fl4 y = *(const fl4*)(p + 4);
    f16x8 r;
    #pragma unroll
    for (int e = 0; e < 4; e++) { r[e] = (f16)x[e]; r[4 + e] = (f16)y[e]; }
    return r;
}

// ---------------- stage 1: men1 = relu(ME@mw1t + mb1)  [A=f32, rows 2048, bx<32]
//                            vis1 = relu(cl_h@vw1t + vb1) [A=f16, rows 1152, bx>=32]
__global__ __launch_bounds__(256) void gemm_s1(const float* __restrict__ Af,
                                               const f16* __restrict__ Ah,
                                               const f16* __restrict__ Wm, const f16* __restrict__ Wv,
                                               const float* __restrict__ bm, const float* __restrict__ bv,
                                               f16* __restrict__ om, f16* __restrict__ ov) {
    int lane = threadIdx.x & 63, w = threadIdx.x >> 6;
    int wr = w >> 1, wc = w & 1;
    int rl = lane & 15, kg = lane >> 4;
    bool isv = blockIdx.x >= 32;
    int mb = isv ? blockIdx.x - 32 : blockIdx.x;
    const f16* Wt = isv ? Wv : Wm;
    const float* bias = isv ? bv : bm;
    f16* out = isv ? ov : om;
    int m0 = mb * 64 + wr * 32, n0 = blockIdx.y * 64 + wc * 32;

    f32x4 acc[2][2] = {};
    const f16* b0p = Wt + (n0 + rl) * 1024 + kg * 8;
    const f16* b1p = b0p + 16 * 1024;
    const float* af0 = Af + (m0 + rl) * 1024 + kg * 8;
    const float* af1 = af0 + 16 * 1024;
    const f16* ah0 = Ah + (m0 + rl) * 1024 + kg * 8;
    const f16* ah1 = ah0 + 16 * 1024;

    for (int k0 = 0; k0 < 1024; k0 += 32) {
        f16x8 a0, a1;
        if (!isv) { a0 = cvt8(af0 + k0); a1 = cvt8(af1 + k0); }
        else      { a0 = *(const f16x8*)(ah0 + k0); a1 = *(const f16x8*)(ah1 + k0); }
        f16x8 b0 = *(const f16x8*)(b0p + k0);
        f16x8 b1 = *(const f16x8*)(b1p + k0);
        acc[0][0] = __builtin_amdgcn_mfma_f32_16x16x32_f16(a0, b0, acc[0][0], 0, 0, 0);
        acc[0][1] = __builtin_amdgcn_mfma_f32_16x16x32_f16(a0, b1, acc[0][1], 0, 0, 0);
        acc[1][0] = __builtin_amdgcn_mfma_f32_16x16x32_f16(a1, b0, acc[1][0], 0, 0, 0);
        acc[1][1] = __builtin_amdgcn_mfma_f32_16x16x32_f16(a1, b1, acc[1][1], 0, 0, 0);
    }
    #pragma unroll
    for (int fi = 0; fi < 2; fi++)
        #pragma unroll
        for (int fj = 0; fj < 2; fj++) {
            int col = n0 + fj * 16 + rl;
            float bv2 = bias[col];
            #pragma unroll
            for (int r = 0; r < 4; r++) {
                int row = m0 + fi * 16 + kg * 4 + r;
                out[row * 512 + col] = (f16)fmaxf(acc[fi][fj][r] + bv2, 0.f);
            }
        }
}

// ---------------- stage 2: menh = men1@mw2t + mb2; vish = vis1@vw2t + vb2 (K=512)
__global__ __launch_bounds__(256) void gemm_s2(const f16* __restrict__ Am,
                                               const f16* __restrict__ Av,
                                               const f16* __restrict__ Wm, const f16* __restrict__ Wv,
                                               const float* __restrict__ bm, const float* __restrict__ bv,
                                               f16* __restrict__ om, f16* __restrict__ ov) {
    int lane = threadIdx.x & 63, w = threadIdx.x >> 6;
    int wr = w >> 1, wc = w & 1;
    int rl = lane & 15, kg = lane >> 4;
    bool isv = blockIdx.x >= 32;
    int mb = isv ? blockIdx.x - 32 : blockIdx.x;
    const f16* A = isv ? Av : Am;
    const f16* Wt = isv ? Wv : Wm;
    const float* bias = isv ? bv : bm;
    f16* out = isv ? ov : om;
    int m0 = mb * 64 + wr * 32, n0 = blockIdx.y * 64 + wc * 32;

    f32x4 acc[2][2] = {};
    const f16* a0p = A + (m0 + rl) * 512 + kg * 8;
    const f16* a1p = a0p + 16 * 512;
    const f16* b0p = Wt + (n0 + rl) * 512 + kg * 8;
    const f16* b1p = b0p + 16 * 512;

    for (int k0 = 0; k0 < 512; k0 += 32) {
        f16x8 a0 = *(const f16x8*)(a0p + k0);
        f16x8 a1 = *(const f16x8*)(a1p + k0);
        f16x8 b0 = *(const f16x8*)(b0p + k0);
        f16x8 b1 = *(const f16x8*)(b1p + k0);
        acc[0][0] = __builtin_amdgcn_mfma_f32_16x16x32_f16(a0, b0, acc[0][0], 0, 0, 0);
        acc[0][1] = __builtin_amdgcn_mfma_f32_16x16x32_f16(a0, b1, acc[0][1], 0, 0, 0);
        acc[1][0] = __builtin_amdgcn_mfma_f32_16x16x32_f16(a1, b0, acc[1][0], 0, 0, 0);
        acc[1][1] = __builtin_amdgcn_mfma_f32_16x16x32_f16(a1, b1, acc[1][1], 0, 0, 0);
    }
    #pragma unroll
    for (int fi = 0; fi < 2; fi++)
        #pragma unroll
        for (int fj = 0; fj < 2; fj++) {
            int col = n0 + fj * 16 + rl;
            float bv2 = bias[col];
            #pragma unroll
            for (int r = 0; r < 4; r++) {
                int row = m0 + fi * 16 + kg * 4 + r;
                out[row * 512 + col] = (f16)(acc[fi][fj][r] + bv2);
            }
        }
}

// ---------------- fused attention, register-double-buffered K loop ----------------
// grid (2 jt, 36 c, 32 b) = 2304 blocks, 4 waves, launch_bounds(256,3) -> 3 blocks/CU,
// exactly 3 clean rounds. Wave w: j0 = jt*256 + w*64, one c; acc = 64 AGPRs only.
// Explicit 1-deep prefetch: step s+1's 9 loads issue BEFORE step s's 16 MFMAs, so
// L2 latency overlaps compute (R4 showed the compiler won't do this on its own).
// jt-partials -> scratch (no atomics); postproc sums + bias + mask.
__global__ __launch_bounds__(256, 3) void attn_f3(const f16* __restrict__ men,
                                                  const f16* __restrict__ vis,
                                                  const f16* __restrict__ aw1t,
                                                  const float* __restrict__ ab1,
                                                  const float* __restrict__ aw2,
                                                  float* __restrict__ partial) {
    __shared__ float red[4][64];

    int t = threadIdx.x, lane = t & 63, w = t >> 6;
    int jt = blockIdx.x, c = blockIdx.y, b = blockIdx.z;
    int rl = lane & 15, kg = lane >> 4;
    int j0 = jt * 256 + w * 64;

    const f16* menb = men + (b * 64 + rl) * 512 + kg * 8;
    const f16* visb = vis + (b * 36 + c) * 512 + kg * 8;
    const f16* awb  = aw1t + (j0 + rl) * 512 + kg * 8;

    f32x4 acc[4][4] = {};
    f16x8 mmc[4], bfc[4], vvc;
    vvc = *(const f16x8*)visb;
    #pragma unroll
    for (int f = 0; f < 4; f++) {
        mmc[f] = *(const f16x8*)(menb + f * 16 * 512);
        bfc[f] = *(const f16x8*)(awb + f * 16 * 512);
    }

    #pragma unroll
    for (int s = 0; s < 16; s++) {
        f16x8 mmn[4], bfn[4], vvn;
        if (s < 15) {
            int k1 = (s + 1) * 32;
            vvn = *(const f16x8*)(visb + k1);
            #pragma unroll
            for (int f = 0; f < 4; f++) {
                mmn[f] = *(const f16x8*)(menb + f * 16 * 512 + k1);
                bfn[f] = *(const f16x8*)(awb + f * 16 * 512 + k1);
            }
        }
        #pragma unroll
        for (int fi = 0; fi < 4; fi++) {
            f16x8 a = mmc[fi] * vvc;   // packed f16 multiply
            #pragma unroll
            for (int fj = 0; fj < 4; fj++)
                acc[fi][fj] = __builtin_amdgcn_mfma_f32_16x16x32_f16(a, bfc[fj], acc[fi][fj], 0, 0, 0);
        }
        if (s < 15) {
            vvc = vvn;
            #pragma unroll
            for (int f = 0; f < 4; f++) { mmc[f] = mmn[f]; bfc[f] = bfn[f]; }
        }
    }

    // fp32 epilogue: part[m] = sum over this wave's 64 j of relu(acc + ab1[j]) * aw2[j]
    float ab1v[4], aw2v[4];
    #pragma unroll
    for (int fj = 0; fj < 4; fj++) {
        int j = j0 + fj * 16 + rl;
        ab1v[fj] = ab1[j];
        aw2v[fj] = aw2[j];
    }
    float part[4][4];
    #pragma unroll
    for (int fi = 0; fi < 4; fi++)
        #pragma unroll
        for (int r = 0; r < 4; r++) {
            float s = 0.f;
            #pragma unroll
            for (int fj = 0; fj < 4; fj++)
                s += fmaxf(acc[fi][fj][r] + ab1v[fj], 0.f) * aw2v[fj];
            part[fi][r] = s;
        }
    #pragma unroll
    for (int mask = 1; mask < 16; mask <<= 1)
        #pragma unroll
        for (int fi = 0; fi < 4; fi++)
            #pragma unroll
            for (int r = 0; r < 4; r++)
                part[fi][r] += __shfl_xor(part[fi][r], mask);

    // lane (rl, kg) owns (fi = rl>>2, r = rl&3) -> m = (rl>>2)*16 + kg*4 + (rl&3)
    float myv = 0.f;
    #pragma unroll
    for (int fi = 0; fi < 4; fi++)
        #pragma unroll
        for (int r = 0; r < 4; r++)
            myv = (rl == fi * 4 + r) ? part[fi][r] : myv;
    int m = (rl >> 2) * 16 + kg * 4 + (rl & 3);
    red[w][m] = myv;
    __syncthreads();

    if (t < 64) {
        float s = red[0][t] + red[1][t] + red[2][t] + red[3][t];
        partial[((jt * 32 + b) * 64 + t) * 36 + c] = s;
    }
}

// ---------------- post-process: sum jt partials, + ab2, masks, NEG_INF ----------------
__global__ __launch_bounds__(256) void postproc(const float* __restrict__ partial,
                                                const float* __restrict__ mm,
                                                const float* __restrict__ cm,
                                                const float* __restrict__ ab2,
                                                float* __restrict__ out) {
    int i = blockIdx.x * 256 + threadIdx.x;  // < 73728
    int b = i / 2304;
    int rest = i - b * 2304;
    int m = rest / 36, c = rest - m * 36;
    float s = partial[((b) * 64 + m) * 36 + c] + partial[((32 + b) * 64 + m) * 36 + c];
    float v = (s + ab2[0]) * mm[b * 64 + m] * cm[b * 36 + c];
    out[i] = (v != 0.f) ? v : NEG_INF_F;
}

extern "C" void kernel_launch(void* const* d_in, const int* in_sizes, int n_in,
                              void* d_out, int out_size, void* d_ws, size_t ws_size,
                              hipStream_t stream) {
    const float* ME  = (const float*)d_in[0];   // (32,64,1024)
    const float* CL  = (const float*)d_in[1];   // (32,36,1000)
    const float* MM  = (const float*)d_in[2];   // (32,64)
    const float* CM  = (const float*)d_in[3];   // (32,36)
    const float* VW1 = (const float*)d_in[4];   // (1000,512)
    const float* VB1 = (const float*)d_in[5];
    const float* VW2 = (const float*)d_in[6];   // (512,512)
    const float* VB2 = (const float*)d_in[7];
    const float* MW1 = (const float*)d_in[8];   // (1024,512)
    const float* MB1 = (const float*)d_in[9];
    const float* MW2 = (const float*)d_in[10];  // (512,512)
    const float* MB2 = (const float*)d_in[11];
    const float* AW1 = (const float*)d_in[12];  // (512,512)
    const float* AB1 = (const float*)d_in[13];
    const float* AW2 = (const float*)d_in[14];  // (512,1)
    const float* AB2 = (const float*)d_in[15];  // (1,)
    float* out = (float*)d_out;

    char* ws = (char*)d_ws;
    f16* cl_h  = (f16*)ws; ws += (size_t)1152 * 1024 * 2;
    f16* mw1t  = (f16*)ws; ws += (size_t)512 * 1024 * 2;
    f16* vw1t  = (f16*)ws; ws += (size_t)512 * 1024 * 2;
    f16* mw2t  = (f16*)ws; ws += (size_t)512 * 512 * 2;
    f16* vw2t  = (f16*)ws; ws += (size_t)512 * 512 * 2;
    f16* aw1t  = (f16*)ws; ws += (size_t)512 * 512 * 2;
    f16* men1  = (f16*)ws; ws += (size_t)2048 * 512 * 2;
    f16* menh  = (f16*)ws; ws += (size_t)2048 * 512 * 2;
    f16* vis1  = (f16*)ws; ws += (size_t)1152 * 512 * 2;
    f16* vish  = (f16*)ws; ws += (size_t)1152 * 512 * 2;
    float* part = (float*)ws; ws += (size_t)2 * 32 * 64 * 36 * 4;

    prep<<<11776, 256, 0, stream>>>(MW1, VW1, MW2, VW2, AW1, CL,
                                    mw1t, vw1t, mw2t, vw2t, aw1t, cl_h);
    gemm_s1<<<dim3(50, 8), 256, 0, stream>>>(ME, cl_h, mw1t, vw1t, MB1, VB1, men1, vis1);
    gemm_s2<<<dim3(50, 8), 256, 0, stream>>>(men1, vis1, mw2t, vw2t, MB2, VB2, menh, vish);
    attn_f3<<<dim3(2, 36, 32), 256, 0, stream>>>(menh, vish, aw1t, AB1, AW2, part);
    postproc<<<288, 256, 0, stream>>>(part, MM, CM, AB2, out);
}

// Round 11
// 140.330 us; speedup vs baseline: 1.5576x; 1.5491x over previous
//
#include <hip/hip_runtime.h>

typedef _Float16 f16;
typedef _Float16 f16x8 __attribute__((ext_vector_type(8)));
typedef float f32x4 __attribute__((ext_vector_type(4)));
typedef float fl4 __attribute__((ext_vector_type(4)));

#define NEG_INF_F (-1e10f)

__device__ __forceinline__ void stage16(const f16* g, f16* l) {
    __builtin_amdgcn_global_load_lds((const __attribute__((address_space(1))) void*)g,
                                     (__attribute__((address_space(3))) void*)l, 16, 0, 0);
}

// ---------------- prep: all 5 weight transposes + class_labels pad/convert ----------
__global__ __launch_bounds__(256) void prep(const float* __restrict__ mw1,
                                            const float* __restrict__ vw1,
                                            const float* __restrict__ mw2,
                                            const float* __restrict__ vw2,
                                            const float* __restrict__ aw1,
                                            const float* __restrict__ cl,
                                            f16* __restrict__ mw1t, f16* __restrict__ vw1t,
                                            f16* __restrict__ mw2t, f16* __restrict__ vw2t,
                                            f16* __restrict__ aw1t, f16* __restrict__ cl_h) {
    int i = blockIdx.x * 256 + threadIdx.x;
    if (i < 1048576) {
        int seg = i >> 19;
        int j = i & 524287;
        int k = j & 1023, n = j >> 10;
        if (seg == 0) mw1t[n * 1024 + k] = (f16)mw1[k * 512 + n];
        else          vw1t[n * 1024 + k] = (k < 1000) ? (f16)vw1[k * 512 + n] : (f16)0.f;
    } else if (i < 1835008) {
        int j = i - 1048576;
        int seg = j >> 18;
        int r = j & 262143;
        int k = r & 511, n = r >> 9;
        const float* src = (seg == 0) ? mw2 : (seg == 1) ? vw2 : aw1;
        f16* dst = (seg == 0) ? mw2t : (seg == 1) ? vw2t : aw1t;
        dst[n * 512 + k] = (f16)src[k * 512 + n];
    } else {
        int j = i - 1835008;
        int r = j >> 10, k = j & 1023;
        cl_h[j] = (k < 1000) ? (f16)cl[r * 1000 + k] : (f16)0.f;
    }
}

__device__ __forceinline__ f16x8 cvt8(const float* p) {
    fl4 x = *(const fl4*)p;
    fl4 y = *(const fl4*)(p + 4);
    f16x8 r;
    #pragma unroll
    for (int e = 0; e < 4; e++) { r[e] = (f16)x[e]; r[4 + e] = (f16)y[e]; }
    return r;
}

// ---------------- stage 1: men1 = relu(ME@mw1t + mb1)  [A=f32, rows 2048, bx<32]
//                            vis1 = relu(cl_h@vw1t + vb1) [A=f16, rows 1152, bx>=32]
__global__ __launch_bounds__(256) void gemm_s1(const float* __restrict__ Af,
                                               const f16* __restrict__ Ah,
                                               const f16* __restrict__ Wm, const f16* __restrict__ Wv,
                                               const float* __restrict__ bm, const float* __restrict__ bv,
                                               f16* __restrict__ om, f16* __restrict__ ov) {
    int lane = threadIdx.x & 63, w = threadIdx.x >> 6;
    int wr = w >> 1, wc = w & 1;
    int rl = lane & 15, kg = lane >> 4;
    bool isv = blockIdx.x >= 32;
    int mb = isv ? blockIdx.x - 32 : blockIdx.x;
    const f16* Wt = isv ? Wv : Wm;
    const float* bias = isv ? bv : bm;
    f16* out = isv ? ov : om;
    int m0 = mb * 64 + wr * 32, n0 = blockIdx.y * 64 + wc * 32;

    f32x4 acc[2][2] = {};
    const f16* b0p = Wt + (n0 + rl) * 1024 + kg * 8;
    const f16* b1p = b0p + 16 * 1024;
    const float* af0 = Af + (m0 + rl) * 1024 + kg * 8;
    const float* af1 = af0 + 16 * 1024;
    const f16* ah0 = Ah + (m0 + rl) * 1024 + kg * 8;
    const f16* ah1 = ah0 + 16 * 1024;

    for (int k0 = 0; k0 < 1024; k0 += 32) {
        f16x8 a0, a1;
        if (!isv) { a0 = cvt8(af0 + k0); a1 = cvt8(af1 + k0); }
        else      { a0 = *(const f16x8*)(ah0 + k0); a1 = *(const f16x8*)(ah1 + k0); }
        f16x8 b0 = *(const f16x8*)(b0p + k0);
        f16x8 b1 = *(const f16x8*)(b1p + k0);
        acc[0][0] = __builtin_amdgcn_mfma_f32_16x16x32_f16(a0, b0, acc[0][0], 0, 0, 0);
        acc[0][1] = __builtin_amdgcn_mfma_f32_16x16x32_f16(a0, b1, acc[0][1], 0, 0, 0);
        acc[1][0] = __builtin_amdgcn_mfma_f32_16x16x32_f16(a1, b0, acc[1][0], 0, 0, 0);
        acc[1][1] = __builtin_amdgcn_mfma_f32_16x16x32_f16(a1, b1, acc[1][1], 0, 0, 0);
    }
    #pragma unroll
    for (int fi = 0; fi < 2; fi++)
        #pragma unroll
        for (int fj = 0; fj < 2; fj++) {
            int col = n0 + fj * 16 + rl;
            float bv2 = bias[col];
            #pragma unroll
            for (int r = 0; r < 4; r++) {
                int row = m0 + fi * 16 + kg * 4 + r;
                out[row * 512 + col] = (f16)fmaxf(acc[fi][fj][r] + bv2, 0.f);
            }
        }
}

// ---------------- stage 2: menh = men1@mw2t + mb2; vish = vis1@vw2t + vb2 (K=512)
__global__ __launch_bounds__(256) void gemm_s2(const f16* __restrict__ Am,
                                               const f16* __restrict__ Av,
                                               const f16* __restrict__ Wm, const f16* __restrict__ Wv,
                                               const float* __restrict__ bm, const float* __restrict__ bv,
                                               f16* __restrict__ om, f16* __restrict__ ov) {
    int lane = threadIdx.x & 63, w = threadIdx.x >> 6;
    int wr = w >> 1, wc = w & 1;
    int rl = lane & 15, kg = lane >> 4;
    bool isv = blockIdx.x >= 32;
    int mb = isv ? blockIdx.x - 32 : blockIdx.x;
    const f16* A = isv ? Av : Am;
    const f16* Wt = isv ? Wv : Wm;
    const float* bias = isv ? bv : bm;
    f16* out = isv ? ov : om;
    int m0 = mb * 64 + wr * 32, n0 = blockIdx.y * 64 + wc * 32;

    f32x4 acc[2][2] = {};
    const f16* a0p = A + (m0 + rl) * 512 + kg * 8;
    const f16* a1p = a0p + 16 * 512;
    const f16* b0p = Wt + (n0 + rl) * 512 + kg * 8;
    const f16* b1p = b0p + 16 * 512;

    for (int k0 = 0; k0 < 512; k0 += 32) {
        f16x8 a0 = *(const f16x8*)(a0p + k0);
        f16x8 a1 = *(const f16x8*)(a1p + k0);
        f16x8 b0 = *(const f16x8*)(b0p + k0);
        f16x8 b1 = *(const f16x8*)(b1p + k0);
        acc[0][0] = __builtin_amdgcn_mfma_f32_16x16x32_f16(a0, b0, acc[0][0], 0, 0, 0);
        acc[0][1] = __builtin_amdgcn_mfma_f32_16x16x32_f16(a0, b1, acc[0][1], 0, 0, 0);
        acc[1][0] = __builtin_amdgcn_mfma_f32_16x16x32_f16(a1, b0, acc[1][0], 0, 0, 0);
        acc[1][1] = __builtin_amdgcn_mfma_f32_16x16x32_f16(a1, b1, acc[1][1], 0, 0, 0);
    }
    #pragma unroll
    for (int fi = 0; fi < 2; fi++)
        #pragma unroll
        for (int fj = 0; fj < 2; fj++) {
            int col = n0 + fj * 16 + rl;
            float bv2 = bias[col];
            #pragma unroll
            for (int r = 0; r < 4; r++) {
                int row = m0 + fi * 16 + kg * 4 + r;
                out[row * 512 + col] = (f16)(acc[fi][fj][r] + bv2);
            }
        }
}

// ---------------- fused attention, m97-structure (all operands via LDS) ----------------
// grid (36 c, 32 b) = 1152 blocks, 512 thr (8 waves), launch_bounds(512,4) -> 2 blocks/CU
// (LDS 74KB). Per BK=32 step: stage aw 512x32 (32KB) + men 64x32 (4KB) into dbuf LDS via
// global_load_lds ISSUED BEFORE compute (T3 2-phase, one barrier/step); waves read 8
// XOR-swizzled ds_read_b128 frags (pu = kg^(rl&3), even 8-slot spread = conflict-free)
// + 1 broadcast vis load; 16 MFMAs. Wave w owns j in [w*64, w*64+64). Direct masked store.
__global__ __launch_bounds__(512, 4) void attn_f4(const f16* __restrict__ men,
                                                  const f16* __restrict__ vis,
                                                  const f16* __restrict__ aw1t,
                                                  const float* __restrict__ ab1,
                                                  const float* __restrict__ aw2,
                                                  const float* __restrict__ ab2,
                                                  const float* __restrict__ maskm,
                                                  const float* __restrict__ maskc,
                                                  float* __restrict__ out) {
    __shared__ f16 aw_buf[2][16384];   // [buf][row j 0..511][unit 0..3][8 f16], unit swizzled
    __shared__ f16 men_buf[2][2048];   // [buf][row m 0..63][unit 0..3][8 f16], unit swizzled
    __shared__ float red[8][64];

    int t = threadIdx.x, lane = t & 63, w = t >> 6;
    int c = blockIdx.x, b = blockIdx.y;
    int rl = lane & 15, kg = lane >> 4;
    int j0 = w * 64;
    int pu = kg ^ (rl & 3);            // swizzled physical unit for ds_reads

    // staging sources (pre-swizzled global addresses, G21): thread t covers
    // aw rows r*128 + (t>>2), unit t&3 -> logical k8 = (t&3)^(row&3)
    int srow = t >> 2;
    int sk8  = (t & 3) ^ (srow & 3);
    const f16* aw_src  = aw1t + srow * 512 + sk8 * 8;           // + r*128*512 + k0
    const f16* men_src = men + (b * 64 + srow) * 512 + sk8 * 8; // + k0 (t < 256 only)
    const f16* visb = vis + (b * 36 + c) * 512;

    f32x4 acc[4][4] = {};

    // prologue: stage step 0 into buf 0
    #pragma unroll
    for (int r = 0; r < 4; r++)
        stage16(aw_src + r * 128 * 512, &aw_buf[0][(r * 512 + t) * 8]);
    if (t < 256)
        stage16(men_src, &men_buf[0][t * 8]);
    __syncthreads();

    for (int s = 0; s < 16; s++) {
        int cur = s & 1;
        if (s < 15) {  // issue next step's staging FIRST; completes under this step's MFMAs
            int k1 = (s + 1) * 32;
            #pragma unroll
            for (int r = 0; r < 4; r++)
                stage16(aw_src + r * 128 * 512 + k1, &aw_buf[cur ^ 1][(r * 512 + t) * 8]);
            if (t < 256)
                stage16(men_src + k1, &men_buf[cur ^ 1][t * 8]);
        }

        f16x8 vv = *(const f16x8*)(visb + s * 32 + kg * 8);  // quarter-broadcast, L1
        f16x8 mm[4], bf[4];
        #pragma unroll
        for (int fi = 0; fi < 4; fi++)
            mm[fi] = *(const f16x8*)&men_buf[cur][(fi * 16 + rl) * 32 + pu * 8];
        #pragma unroll
        for (int fj = 0; fj < 4; fj++)
            bf[fj] = *(const f16x8*)&aw_buf[cur][(j0 + fj * 16 + rl) * 32 + pu * 8];

        #pragma unroll
        for (int fi = 0; fi < 4; fi++) {
            f16x8 a = mm[fi] * vv;   // packed f16 multiply
            #pragma unroll
            for (int fj = 0; fj < 4; fj++)
                acc[fi][fj] = __builtin_amdgcn_mfma_f32_16x16x32_f16(a, bf[fj], acc[fi][fj], 0, 0, 0);
        }
        __syncthreads();  // drains staging vmcnt; protects dbuf swap
    }

    // fp32 epilogue: part[m] = sum over this wave's 64 j of relu(acc + ab1[j]) * aw2[j]
    float ab1v[4], aw2v[4];
    #pragma unroll
    for (int fj = 0; fj < 4; fj++) {
        int j = j0 + fj * 16 + rl;
        ab1v[fj] = ab1[j];
        aw2v[fj] = aw2[j];
    }
    float part[4][4];
    #pragma unroll
    for (int fi = 0; fi < 4; fi++)
        #pragma unroll
        for (int r = 0; r < 4; r++) {
            float s = 0.f;
            #pragma unroll
            for (int fj = 0; fj < 4; fj++)
                s += fmaxf(acc[fi][fj][r] + ab1v[fj], 0.f) * aw2v[fj];
            part[fi][r] = s;
        }
    #pragma unroll
    for (int mask = 1; mask < 16; mask <<= 1)
        #pragma unroll
        for (int fi = 0; fi < 4; fi++)
            #pragma unroll
            for (int r = 0; r < 4; r++)
                part[fi][r] += __shfl_xor(part[fi][r], mask);

    // lane (rl, kg) owns (fi = rl>>2, r = rl&3) -> m = (rl>>2)*16 + kg*4 + (rl&3)
    float myv = 0.f;
    #pragma unroll
    for (int fi = 0; fi < 4; fi++)
        #pragma unroll
        for (int r = 0; r < 4; r++)
            myv = (rl == fi * 4 + r) ? part[fi][r] : myv;
    int m = (rl >> 2) * 16 + kg * 4 + (rl & 3);
    red[w][m] = myv;
    __syncthreads();

    if (t < 64) {
        float s = 0.f;
        #pragma unroll
        for (int ww = 0; ww < 8; ww++) s += red[ww][t];
        float v = (s + ab2[0]) * maskm[b * 64 + t] * maskc[b * 36 + c];
        out[(b * 64 + t) * 36 + c] = (v != 0.f) ? v : NEG_INF_F;
    }
}

extern "C" void kernel_launch(void* const* d_in, const int* in_sizes, int n_in,
                              void* d_out, int out_size, void* d_ws, size_t ws_size,
                              hipStream_t stream) {
    const float* ME  = (const float*)d_in[0];   // (32,64,1024)
    const float* CL  = (const float*)d_in[1];   // (32,36,1000)
    const float* MM  = (const float*)d_in[2];   // (32,64)
    const float* CM  = (const float*)d_in[3];   // (32,36)
    const float* VW1 = (const float*)d_in[4];   // (1000,512)
    const float* VB1 = (const float*)d_in[5];
    const float* VW2 = (const float*)d_in[6];   // (512,512)
    const float* VB2 = (const float*)d_in[7];
    const float* MW1 = (const float*)d_in[8];   // (1024,512)
    const float* MB1 = (const float*)d_in[9];
    const float* MW2 = (const float*)d_in[10];  // (512,512)
    const float* MB2 = (const float*)d_in[11];
    const float* AW1 = (const float*)d_in[12];  // (512,512)
    const float* AB1 = (const float*)d_in[13];
    const float* AW2 = (const float*)d_in[14];  // (512,1)
    const float* AB2 = (const float*)d_in[15];  // (1,)
    float* out = (float*)d_out;

    char* ws = (char*)d_ws;
    f16* cl_h  = (f16*)ws; ws += (size_t)1152 * 1024 * 2;
    f16* mw1t  = (f16*)ws; ws += (size_t)512 * 1024 * 2;
    f16* vw1t  = (f16*)ws; ws += (size_t)512 * 1024 * 2;
    f16* mw2t  = (f16*)ws; ws += (size_t)512 * 512 * 2;
    f16* vw2t  = (f16*)ws; ws += (size_t)512 * 512 * 2;
    f16* aw1t  = (f16*)ws; ws += (size_t)512 * 512 * 2;
    f16* men1  = (f16*)ws; ws += (size_t)2048 * 512 * 2;
    f16* menh  = (f16*)ws; ws += (size_t)2048 * 512 * 2;
    f16* vis1  = (f16*)ws; ws += (size_t)1152 * 512 * 2;
    f16* vish  = (f16*)ws; ws += (size_t)1152 * 512 * 2;

    prep<<<11776, 256, 0, stream>>>(MW1, VW1, MW2, VW2, AW1, CL,
                                    mw1t, vw1t, mw2t, vw2t, aw1t, cl_h);
    gemm_s1<<<dim3(50, 8), 256, 0, stream>>>(ME, cl_h, mw1t, vw1t, MB1, VB1, men1, vis1);
    gemm_s2<<<dim3(50, 8), 256, 0, stream>>>(men1, vis1, mw2t, vw2t, MB2, VB2, menh, vish);
    attn_f4<<<dim3(36, 32), 512, 0, stream>>>(menh, vish, aw1t, AB1, AW2, AB2, MM, CM, out);
}

// Round 12
// 115.813 us; speedup vs baseline: 1.8873x; 1.2117x over previous
//
#include <hip/hip_runtime.h>

typedef _Float16 f16;
typedef _Float16 f16x8 __attribute__((ext_vector_type(8)));
typedef float f32x4 __attribute__((ext_vector_type(4)));

#define NEG_INF_F (-1e10f)

__device__ __forceinline__ void stage16(const f16* g, f16* l) {
    __builtin_amdgcn_global_load_lds((const __attribute__((address_space(1))) void*)g,
                                     (__attribute__((address_space(3))) void*)l, 16, 0, 0);
}

// ---------------- prep: me_h + weight transposes + class_labels pad ----------
__global__ __launch_bounds__(256) void prep(const float* __restrict__ me,
                                            const float* __restrict__ mw1,
                                            const float* __restrict__ vw1,
                                            const float* __restrict__ mw2,
                                            const float* __restrict__ vw2,
                                            const float* __restrict__ aw1,
                                            const float* __restrict__ cl,
                                            f16* __restrict__ me_h,
                                            f16* __restrict__ mw1t, f16* __restrict__ vw1t,
                                            f16* __restrict__ mw2t, f16* __restrict__ vw2t,
                                            f16* __restrict__ aw1t, f16* __restrict__ cl_h) {
    int i = blockIdx.x * 256 + threadIdx.x;
    if (i < 2097152) {
        me_h[i] = (f16)me[i];
        return;
    }
    int j = i - 2097152;
    if (j < 1048576) {
        int seg = j >> 19;
        int jj = j & 524287;
        int k = jj & 1023, n = jj >> 10;
        if (seg == 0) mw1t[n * 1024 + k] = (f16)mw1[k * 512 + n];
        else          vw1t[n * 1024 + k] = (k < 1000) ? (f16)vw1[k * 512 + n] : (f16)0.f;
        return;
    }
    j -= 1048576;
    if (j < 786432) {
        int seg = j >> 18;
        int r = j & 262143;
        int k = r & 511, n = r >> 9;
        const float* src = (seg == 0) ? mw2 : (seg == 1) ? vw2 : aw1;
        f16* dst = (seg == 0) ? mw2t : (seg == 1) ? vw2t : aw1t;
        dst[n * 512 + k] = (f16)src[k * 512 + n];
        return;
    }
    j -= 786432;
    int r = j >> 10, k = j & 1023;
    cl_h[j] = (k < 1000) ? (f16)cl[r * 1000 + k] : (f16)0.f;
}

// ---------------- staged 1-wave GEMM: out = act(A @ Wt^T + bias), 32x32 tile ----------
__global__ __launch_bounds__(64) void gemm_stg(const f16* __restrict__ Am,
                                               const f16* __restrict__ Av,
                                               const f16* __restrict__ Wm,
                                               const f16* __restrict__ Wv,
                                               const float* __restrict__ bm,
                                               const float* __restrict__ bv,
                                               f16* __restrict__ om,
                                               f16* __restrict__ ov,
                                               int K, int relu) {
    __shared__ f16 ab[2][1024], bb[2][1024];  // [buf][row 0..31][unit 0..3][8 f16]

    int t = threadIdx.x;
    int rl = t & 15, kg = t >> 4;
    bool isv = blockIdx.x >= 64;
    int mb = isv ? blockIdx.x - 64 : blockIdx.x;
    const f16* A = isv ? Av : Am;
    const f16* Wt = isv ? Wv : Wm;
    const float* bias = isv ? bv : bm;
    f16* out = isv ? ov : om;
    int m0 = mb * 32, n0 = blockIdx.y * 32;
    int pu = kg ^ ((rl >> 1) & 3);

    int srow = t >> 2;
    int sk8 = (t & 3) ^ ((srow >> 1) & 3);
    const f16* a_src = A + (m0 + srow) * K + sk8 * 8;
    const f16* b_src = Wt + (n0 + srow) * K + sk8 * 8;
    int nsteps = K >> 5;

    f32x4 acc[2][2] = {};

    #pragma unroll
    for (int i = 0; i < 2; i++) {
        stage16(a_src + i * 16 * K, &ab[0][i * 512 + t * 8]);
        stage16(b_src + i * 16 * K, &bb[0][i * 512 + t * 8]);
    }
    __syncthreads();

    for (int s = 0; s < nsteps; s++) {
        int cur = s & 1;
        if (s + 1 < nsteps) {
            int k1 = (s + 1) * 32;
            #pragma unroll
            for (int i = 0; i < 2; i++) {
                stage16(a_src + i * 16 * K + k1, &ab[cur ^ 1][i * 512 + t * 8]);
                stage16(b_src + i * 16 * K + k1, &bb[cur ^ 1][i * 512 + t * 8]);
            }
        }
        f16x8 af[2], bf[2];
        #pragma unroll
        for (int f = 0; f < 2; f++) {
            af[f] = *(const f16x8*)&ab[cur][(f * 16 + rl) * 32 + pu * 8];
            bf[f] = *(const f16x8*)&bb[cur][(f * 16 + rl) * 32 + pu * 8];
        }
        #pragma unroll
        for (int fi = 0; fi < 2; fi++)
            #pragma unroll
            for (int fj = 0; fj < 2; fj++)
                acc[fi][fj] = __builtin_amdgcn_mfma_f32_16x16x32_f16(af[fi], bf[fj], acc[fi][fj], 0, 0, 0);
        __syncthreads();
    }

    #pragma unroll
    for (int fi = 0; fi < 2; fi++)
        #pragma unroll
        for (int fj = 0; fj < 2; fj++) {
            int col = n0 + fj * 16 + rl;
            float bv2 = bias[col];
            #pragma unroll
            for (int r = 0; r < 4; r++) {
                int row = m0 + fi * 16 + kg * 4 + r;
                float v = acc[fi][fj][r] + bv2;
                if (relu) v = fmaxf(v, 0.f);
                out[row * 512 + col] = (f16)v;
            }
        }
}

// ---------------- fused attention, c-paired (8 LDS reads -> 32 MFMAs) ----------------
__global__ __launch_bounds__(256, 2) void attn_f5(const f16* __restrict__ men,
                                                  const f16* __restrict__ vis,
                                                  const f16* __restrict__ aw1t,
                                                  const float* __restrict__ ab1,
                                                  const float* __restrict__ aw2,
                                                  const float* __restrict__ ab2,
                                                  const float* __restrict__ maskm,
                                                  const float* __restrict__ maskc,
                                                  float* __restrict__ out) {
    __shared__ f16 awb[2][8192];    // [buf][row 0..255][unit 0..3][8 f16]
    __shared__ f16 mnb[2][2048];    // [buf][row 0..63][unit][8]
    __shared__ float red[4][2][64];

    int t = threadIdx.x, lane = t & 63, w = t >> 6;
    int cp = blockIdx.x, b = blockIdx.y, c0 = cp * 2;
    int rl = lane & 15, kg = lane >> 4;
    int pu = kg ^ ((rl >> 1) & 3);

    int srow = t >> 2;  // 0..63
    int sk8 = (t & 3) ^ ((srow >> 1) & 3);
    const f16* aw_src = aw1t + srow * 512 + sk8 * 8;
    const f16* mn_src = men + (b * 64 + srow) * 512 + sk8 * 8;
    const f16* visb = vis + (b * 36 + c0) * 512;

    f32x4 acc0[4][4] = {}, acc1[4][4] = {};
    float psum0[4][4] = {}, psum1[4][4] = {};

    #pragma unroll
    for (int i = 0; i < 4; i++)
        stage16(aw_src + i * 64 * 512, &awb[0][i * 2048 + t * 8]);
    stage16(mn_src, &mnb[0][t * 8]);
    __syncthreads();

    for (int ss = 0; ss < 32; ss++) {
        int p = ss >> 4, s = ss & 15, cur = ss & 1;
        if (ss < 31) {
            int pn = (ss + 1) >> 4, sn = (ss + 1) & 15;
            #pragma unroll
            for (int i = 0; i < 4; i++)
                stage16(aw_src + (pn * 256 + i * 64) * 512 + sn * 32,
                        &awb[cur ^ 1][i * 2048 + t * 8]);
            stage16(mn_src + sn * 32, &mnb[cur ^ 1][t * 8]);
        }

        f16x8 vv0 = *(const f16x8*)(visb + s * 32 + kg * 8);
        f16x8 vv1 = *(const f16x8*)(visb + 512 + s * 32 + kg * 8);
        f16x8 bf[4];
        #pragma unroll
        for (int fj = 0; fj < 4; fj++)
            bf[fj] = *(const f16x8*)&awb[cur][(w * 64 + fj * 16 + rl) * 32 + pu * 8];
        #pragma unroll
        for (int fi = 0; fi < 4; fi++) {
            f16x8 mm = *(const f16x8*)&mnb[cur][(fi * 16 + rl) * 32 + pu * 8];
            f16x8 a0 = mm * vv0;
            #pragma unroll
            for (int fj = 0; fj < 4; fj++)
                acc0[fi][fj] = __builtin_amdgcn_mfma_f32_16x16x32_f16(a0, bf[fj], acc0[fi][fj], 0, 0, 0);
            f16x8 a1 = mm * vv1;
            #pragma unroll
            for (int fj = 0; fj < 4; fj++)
                acc1[fi][fj] = __builtin_amdgcn_mfma_f32_16x16x32_f16(a1, bf[fj], acc1[fi][fj], 0, 0, 0);
        }
        __syncthreads();

        if (s == 15) {  // end of pass p: fold acc -> psum, reset acc
            int j0 = p * 256 + w * 64;
            float ab1v[4], aw2v[4];
            #pragma unroll
            for (int fj = 0; fj < 4; fj++) {
                int j = j0 + fj * 16 + rl;
                ab1v[fj] = ab1[j];
                aw2v[fj] = aw2[j];
            }
            float part0[4][4], part1[4][4];
            #pragma unroll
            for (int fi = 0; fi < 4; fi++)
                #pragma unroll
                for (int r = 0; r < 4; r++) {
                    float s0 = 0.f, s1 = 0.f;
                    #pragma unroll
                    for (int fj = 0; fj < 4; fj++) {
                        s0 += fmaxf(acc0[fi][fj][r] + ab1v[fj], 0.f) * aw2v[fj];
                        s1 += fmaxf(acc1[fi][fj][r] + ab1v[fj], 0.f) * aw2v[fj];
                    }
                    part0[fi][r] = s0;
                    part1[fi][r] = s1;
                }
            #pragma unroll
            for (int mask = 1; mask < 16; mask <<= 1)
                #pragma unroll
                for (int fi = 0; fi < 4; fi++)
                    #pragma unroll
                    for (int r = 0; r < 4; r++) {
                        part0[fi][r] += __shfl_xor(part0[fi][r], mask);
                        part1[fi][r] += __shfl_xor(part1[fi][r], mask);
                    }
            #pragma unroll
            for (int fi = 0; fi < 4; fi++)
                #pragma unroll
                for (int r = 0; r < 4; r++) {
                    psum0[fi][r] += part0[fi][r];
                    psum1[fi][r] += part1[fi][r];
                }
            #pragma unroll
            for (int fi = 0; fi < 4; fi++)
                #pragma unroll
                for (int fj = 0; fj < 4; fj++) {
                    acc0[fi][fj] = (f32x4){0.f, 0.f, 0.f, 0.f};
                    acc1[fi][fj] = (f32x4){0.f, 0.f, 0.f, 0.f};
                }
        }
    }

    float myv0 = 0.f, myv1 = 0.f;
    #pragma unroll
    for (int fi = 0; fi < 4; fi++)
        #pragma unroll
        for (int r = 0; r < 4; r++) {
            bool sel = (rl == fi * 4 + r);
            myv0 = sel ? psum0[fi][r] : myv0;
            myv1 = sel ? psum1[fi][r] : myv1;
        }
    int m = (rl >> 2) * 16 + kg * 4 + (rl & 3);
    red[w][0][m] = myv0;
    red[w][1][m] = myv1;
    __syncthreads();

    if (t < 128) {
        int ci = t >> 6, m2 = t & 63;
        float s = red[0][ci][m2] + red[1][ci][m2] + red[2][ci][m2] + red[3][ci][m2];
        int c = c0 + ci;
        float v = (s + ab2[0]) * maskm[b * 64 + m2] * maskc[b * 36 + c];
        out[(b * 64 + m2) * 36 + c] = (v != 0.f) ? v : NEG_INF_F;
    }
}

extern "C" void kernel_launch(void* const* d_in, const int* in_sizes, int n_in,
                              void* d_out, int out_size, void* d_ws, size_t ws_size,
                              hipStream_t stream) {
    const float* ME  = (const float*)d_in[0];   // (32,64,1024)
    const float* CL  = (const float*)d_in[1];   // (32,36,1000)
    const float* MM  = (const float*)d_in[2];   // (32,64)
    const float* CM  = (const float*)d_in[3];   // (32,36)
    const float* VW1 = (const float*)d_in[4];   // (1000,512)
    const float* VB1 = (const float*)d_in[5];
    const float* VW2 = (const float*)d_in[6];   // (512,512)
    const float* VB2 = (const float*)d_in[7];
    const float* MW1 = (const float*)d_in[8];   // (1024,512)
    const float* MB1 = (const float*)d_in[9];
    const float* MW2 = (const float*)d_in[10];  // (512,512)
    const float* MB2 = (const float*)d_in[11];
    const float* AW1 = (const float*)d_in[12];  // (512,512)
    const float* AB1 = (const float*)d_in[13];
    const float* AW2 = (const float*)d_in[14];  // (512,1)
    const float* AB2 = (const float*)d_in[15];  // (1,)
    float* out = (float*)d_out;

    char* ws = (char*)d_ws;
    f16* me_h  = (f16*)ws; ws += (size_t)2048 * 1024 * 2;
    f16* cl_h  = (f16*)ws; ws += (size_t)1152 * 1024 * 2;
    f16* mw1t  = (f16*)ws; ws += (size_t)512 * 1024 * 2;
    f16* vw1t  = (f16*)ws; ws += (size_t)512 * 1024 * 2;
    f16* mw2t  = (f16*)ws; ws += (size_t)512 * 512 * 2;
    f16* vw2t  = (f16*)ws; ws += (size_t)512 * 512 * 2;
    f16* aw1t  = (f16*)ws; ws += (size_t)512 * 512 * 2;
    f16* men1  = (f16*)ws; ws += (size_t)2048 * 512 * 2;
    f16* menh  = (f16*)ws; ws += (size_t)2048 * 512 * 2;
    f16* vis1  = (f16*)ws; ws += (size_t)1152 * 512 * 2;
    f16* vish  = (f16*)ws; ws += (size_t)1152 * 512 * 2;

    prep<<<19968, 256, 0, stream>>>(ME, MW1, VW1, MW2, VW2, AW1, CL,
                                    me_h, mw1t, vw1t, mw2t, vw2t, aw1t, cl_h);
    gemm_stg<<<dim3(100, 16), 64, 0, stream>>>(me_h, cl_h, mw1t, vw1t, MB1, VB1,
                                               men1, vis1, 1024, 1);
    gemm_stg<<<dim3(100, 16), 64, 0, stream>>>(men1, vis1, mw2t, vw2t, MB2, VB2,
                                               menh, vish, 512, 0);
    attn_f5<<<dim3(18, 32), 256, 0, stream>>>(menh, vish, aw1t, AB1, AW2, AB2, MM, CM, out);
}